// Round 3
// baseline (204.444 us; speedup 1.0000x reference)
//
#include <hip/hip_runtime.h>
#include <hip/hip_bf16.h>

#define NC 24
#define BT 16

typedef __attribute__((ext_vector_type(8))) short bf16x8;
typedef __attribute__((ext_vector_type(4))) float f32x4;
typedef __attribute__((ext_vector_type(2))) float f32x2;

struct Params {
  const float* x[6];
  const float* W[6];
  const float* cg;
  float* out;
  unsigned short* Wb;   // ws: W pre-swizzled to bf16 B-fragment order (4,091,904 B)
};

constexpr int NPAIRS_C[6] = {6, 15, 21, 24, 24, 21};
constexpr int POFF_C[6]   = {0, 6, 21, 42, 66, 90};
constexpr size_t WBASE_C[6] = {0, 110592, 387072, 774144, 1216512, 1658880};
constexpr int KL_C[6]  = {3456, 8640, 12096, 13824, 13824, 12096};
constexpr int LOFF_C[6] = {0, 1, 4, 9, 16, 25};   // row offset of l in xall (cumsum 2l+1)

constexpr int TL1[111] = {
  0,1,2,3,4,5,
  0,1,1,1,2,2,2,3,3,3,4,4,4,5,5,
  0,1,1,1,2,2,2,2,2,3,3,3,3,3,4,4,4,4,5,5,5,
  0,1,1,1,2,2,2,2,2,3,3,3,3,3,3,4,4,4,4,4,5,5,5,5,
  0,1,1,1,2,2,2,2,3,3,3,3,3,4,4,4,4,4,4,5,5,5,5,5,
  0,1,1,2,2,2,3,3,3,3,4,4,4,4,4,5,5,5,5,5,5
};
constexpr int TL2[111] = {
  1,0,1,2,1,2,3,2,3,4,3,4,5,4,5,   // placeholder guard (overwritten below) -- see real table
  0,0,0,0,0,0,0,0,0,0,0,0,0,0,0,0,0,0,0,0,0,
  0,0,0,0,0,0,0,0,0,0,0,0,0,0,0,0,0,0,0,0,0,0,0,0,
  0,0,0,0,0,0,0,0,0,0,0,0,0,0,0,0,0,0,0,0,0,0,0,0,
  0,0,0,0,0,0,0,0,0,0,0,0,0,0,0,0,0,0,0,0,0,0,0,0
};
// Real TL2 (the above initializer was a typo hazard; define properly):
constexpr int TL2R[111] = {
  0,1,2,3,4,5,
  1,0,1,2,1,2,3,2,3,4,3,4,5,4,5,
  2,1,2,3,0,1,2,3,4,1,2,3,4,5,2,3,4,5,3,4,5,
  3,2,3,4,1,2,3,4,5,0,1,2,3,4,5,1,2,3,4,5,2,3,4,5,
  4,3,4,5,2,3,4,5,1,2,3,4,5,0,1,2,3,4,5,1,2,3,4,5,
  5,4,5,3,4,5,2,3,4,5,1,2,3,4,5,0,1,2,3,4,5
};

// (l, m') blocks ordered heavy-l first for dispatch balance
__constant__ int c_mb_l[36] = {3,3,3,3,3,3,3, 4,4,4,4,4,4,4,4,4, 5,5,5,5,5,5,5,5,5,5,5, 2,2,2,2,2, 1,1,1, 0};
__constant__ int c_mb_m[36] = {0,1,2,3,4,5,6, 0,1,2,3,4,5,6,7,8, 0,1,2,3,4,5,6,7,8,9,10, 0,1,2,3,4, 0,1,2, 0};

// ---------- W swizzle: fp32 [h][k] -> bf16 B-fragment stream (coalesced reads) ----------
template<int L>
__device__ __forceinline__ void swz(const Params& P, int u8) {
  constexpr int KL = KL_C[L];
  constexpr int KL8 = KL / 8;
  if (u8 >= 32 * KL8) return;
  const int h  = u8 / KL8;          // compile-time divisor -> magic mul
  const int k  = (u8 - h * KL8) * 8;
  const int pair = k / 576;
  const int kin  = k - pair * 576;
  const int kc = kin >> 5;
  const int g  = (kin >> 3) & 3;
  const float* src = P.W[L] + (size_t)h * KL + k;
  f32x4 v0 = *(const f32x4*)src;
  f32x4 v1 = *(const f32x4*)(src + 4);
  union { __hip_bfloat162 h2; unsigned int u; } z;
  unsigned int o0, o1, o2, o3;
  z.h2 = __float22bfloat162_rn(make_float2(v0.x, v0.y)); o0 = z.u;
  z.h2 = __float22bfloat162_rn(make_float2(v0.z, v0.w)); o1 = z.u;
  z.h2 = __float22bfloat162_rn(make_float2(v1.x, v1.y)); o2 = z.u;
  z.h2 = __float22bfloat162_rn(make_float2(v1.z, v1.w)); o3 = z.u;
  const size_t dst = WBASE_C[L] + (size_t)pair * 18432 + kc * 1024 + (h >> 4) * 512
                   + ((size_t)(g * 16 + (h & 15))) * 8;
  *(uint4*)(P.Wb + dst) = make_uint4(o0, o1, o2, o3);
}

__global__ __launch_bounds__(256)
void swizzle_W(Params P) {
  const int u8 = blockIdx.x * 256 + threadIdx.x;
  switch (blockIdx.y) {
    case 0: swz<0>(P, u8); break;
    case 1: swz<1>(P, u8); break;
    case 2: swz<2>(P, u8); break;
    case 3: swz<3>(P, u8); break;
    case 4: swz<4>(P, u8); break;
    default: swz<5>(P, u8); break;
  }
}

// ---------- LDS layout (bytes) ----------
// xall: [36 rows][stride 388 f32] = 55,872  (row = LOFF[l]+i, col = b*24+c)
//   stride 388: 388%32==4 -> adjacent rows shift 4 banks (<=2-way, free); 1552B row = 16B aligned
#define XALL_B 0
#define PB_B   55872     // [16][584] bf16 = 18,688
#define CG_B   74560     // [NP][12] f32 <= 1,152
#define SMEM_BYTES 75712 // 2 blocks/CU

template<int L>
__device__ __forceinline__ void body(const Params& P, const int mp, const int btile) {
  constexpr int NP  = NPAIRS_C[L];
  constexpr int OFF = POFF_C[L];
  extern __shared__ char smem[];
  float* xall = (float*)(smem + XALL_B);
  unsigned short* Pb = (unsigned short*)(smem + PB_B);
  float* cgall = (float*)(smem + CG_B);
  float* red = (float*)(smem + PB_B);   // alias Pb after final GEMM: [4][16][32] f32

  const int t = threadIdx.x;
  const int lane = t & 63;
  const int w = t >> 6;
  const int b0 = btile * BT;

  // ---- stage ALL x once, transposed: xall[(LOFF[l]+i)*388 + b*24+c] ----
#pragma unroll
  for (int l = 0; l < 6; ++l) {
    const int n = 2 * l + 1;
    const float* src = P.x[l] + (size_t)b0 * NC * n;
    const int tot = BT * NC * n;
    for (int e = t; e < tot; e += 256) {
      const int bc = e / n;             // compile-time divisor
      const int i  = e - bc * n;
      xall[(LOFF_C[l] + i) * 388 + bc] = src[e];
    }
  }
  // ---- stage ALL cg diagonals for this (L, mp) once ----
  for (int e = t; e < NP * 11; e += 256) {
    const int pi = e / 11, i = e - pi * 11;
    const int l1 = TL1[OFF + pi], l2 = TL2R[OFF + pi];
    const int j = mp + l1 + l2 - L - i;
    float v = 0.f;
    if (i <= 2 * l1 && j >= 0 && j <= 2 * l2)
      v = P.cg[((size_t)(((l1 * 6 + l2) * 6 + L) * 11 + mp) * 11 + i) * 11 + j];
    cgall[pi * 12 + i] = v;
  }
  __syncthreads();

  f32x4 acc0 = {0.f, 0.f, 0.f, 0.f}, acc1 = {0.f, 0.f, 0.f, 0.f};

  // p-compute mapping: thread = (b = t>>4, c-triple = (t>>1)&7, d-half = t&1)
  const int p_dh = t & 1;
  const int p_ct = (t >> 1) & 7;
  const int p_b  = t >> 4;
  const int colb = p_b * 24;            // xall column base for this thread's b

  // MFMA A-fragment base: lane holds P[b=lane&15][k=(lane>>4)*8 + e]
  const unsigned short* pb_frag = Pb + (lane & 15) * 584 + (lane >> 4) * 8;
  unsigned short* pb_dst = Pb + p_b * 584 + (p_ct * 3) * 24 + p_dh * 12;

#pragma unroll
  for (int pi = 0; pi < NP; ++pi) {
    const int l1 = TL1[OFF + pi], l2 = TL2R[OFF + pi];   // fold via unroll
    const int n1 = 2 * l1 + 1, n2 = 2 * l2 + 1;
    const int mK0 = mp + l1 + l2 - L;
    const int lo = mK0 - (n2 - 1);
    const int i0 = lo > 0 ? lo : 0;
    const int i1 = (n1 - 1) < mK0 ? (n1 - 1) : mK0;

    // ---- p-compute: p[b, 3 c's, 12 d's] for this m' ----
    f32x2 p2[3][6];
#pragma unroll
    for (int q = 0; q < 3; ++q)
#pragma unroll
      for (int d2 = 0; d2 < 6; ++d2) p2[q][d2] = (f32x2){0.f, 0.f};

    const float* x1p = xall + (LOFF_C[l1] + i0) * 388 + colb + p_ct * 3;
    const float* x2p = xall + (LOFF_C[l2] + (mK0 - i0)) * 388 + colb + p_dh * 12;
    const float* cgp = cgall + pi * 12 + i0;
    for (int i = i0; i <= i1; ++i) {
      const float cgv = *cgp++;
      f32x2 xv[6];
      *(f32x4*)&xv[0] = *(const f32x4*)x2p;
      *(f32x4*)&xv[2] = *(const f32x4*)(x2p + 4);
      *(f32x4*)&xv[4] = *(const f32x4*)(x2p + 8);
      const float s0 = cgv * x1p[0];
      const float s1 = cgv * x1p[1];
      const float s2 = cgv * x1p[2];
      const f32x2 sv0 = {s0, s0}, sv1 = {s1, s1}, sv2 = {s2, s2};
#pragma unroll
      for (int d2 = 0; d2 < 6; ++d2) {
        p2[0][d2] += sv0 * xv[d2];
        p2[1][d2] += sv1 * xv[d2];
        p2[2][d2] += sv2 * xv[d2];
      }
      x1p += 388; x2p -= 388;
    }
    // pack bf16 -> Pb
#pragma unroll
    for (int q = 0; q < 3; ++q) {
      unsigned int uu[6];
#pragma unroll
      for (int d2 = 0; d2 < 6; ++d2) {
        union { __hip_bfloat162 h2; unsigned int u; } z;
        z.h2 = __float22bfloat162_rn(make_float2(p2[q][d2].x, p2[q][d2].y));
        uu[d2] = z.u;
      }
      uint2* dst = (uint2*)(pb_dst + q * 24);
      dst[0] = make_uint2(uu[0], uu[1]);
      dst[1] = make_uint2(uu[2], uu[3]);
      dst[2] = make_uint2(uu[4], uu[5]);
    }
    __syncthreads();   // Pb ready

    // ---- MFMA GEMM: wave w -> k-chunks kc%4==w, both h-halves ----
    {
      const unsigned short* wbp = P.Wb + WBASE_C[L] + (size_t)pi * 18432 + lane * 8;
      for (int kc = w; kc < 18; kc += 4) {
        bf16x8 af  = *(const bf16x8*)(pb_frag + kc * 32);
        bf16x8 wf0 = *(const bf16x8*)(wbp + kc * 1024);
        bf16x8 wf1 = *(const bf16x8*)(wbp + kc * 1024 + 512);
        acc0 = __builtin_amdgcn_mfma_f32_16x16x32_bf16(af, wf0, acc0, 0, 0, 0);
        acc1 = __builtin_amdgcn_mfma_f32_16x16x32_bf16(af, wf1, acc1, 0, 0, 0);
      }
    }
    __syncthreads();   // GEMM done reading Pb (next pair rewrites it; also guards red alias)
  }

  // ---- cross-wave reduce (red aliases Pb) + store ----
  {
    const int n = lane & 15, g4 = lane >> 4;
#pragma unroll
    for (int r = 0; r < 4; ++r) {         // C/D: col=lane&15, row=(lane>>4)*4+reg
      red[(w * 16 + g4 * 4 + r) * 32 + n] = acc0[r];
      red[(w * 16 + g4 * 4 + r) * 32 + 16 + n] = acc1[r];
    }
  }
  __syncthreads();
#pragma unroll
  for (int it = 0; it < 2; ++it) {
    const int idx = t + 256 * it;         // 512 outputs: 16 b x 32 h
    const int b = idx >> 5, h = idx & 31;
    const float v = red[b * 32 + h] + red[512 + b * 32 + h]
                  + red[1024 + b * 32 + h] + red[1536 + b * 32 + h];
    P.out[(size_t)(b0 + b) * 1152 + h * 36 + L * L + mp] = v;
  }
}

__global__ __launch_bounds__(256, 2)
void CGLayer_main(Params P) {
  const int mb = blockIdx.x;
  const int l = c_mb_l[mb], mp = c_mb_m[mb];
  const int btile = blockIdx.y;
  switch (l) {
    case 0: body<0>(P, mp, btile); break;
    case 1: body<1>(P, mp, btile); break;
    case 2: body<2>(P, mp, btile); break;
    case 3: body<3>(P, mp, btile); break;
    case 4: body<4>(P, mp, btile); break;
    default: body<5>(P, mp, btile); break;
  }
}

extern "C" void kernel_launch(void* const* d_in, const int* in_sizes, int n_in,
                              void* d_out, int out_size, void* d_ws, size_t ws_size,
                              hipStream_t stream) {
  Params P;
  for (int i = 0; i < 6; ++i) P.x[i] = (const float*)d_in[i];
  for (int i = 0; i < 6; ++i) P.W[i] = (const float*)d_in[6 + i];
  P.cg  = (const float*)d_in[12];
  P.out = (float*)d_out;
  P.Wb  = (unsigned short*)d_ws;   // needs 4,091,904 bytes

  dim3 sg(216, 6);
  swizzle_W<<<sg, 256, 0, stream>>>(P);
  dim3 grid(36, 16);
  CGLayer_main<<<grid, 256, SMEM_BYTES, stream>>>(P);
}

// Round 4
// 168.281 us; speedup vs baseline: 1.2149x; 1.2149x over previous
//
#include <hip/hip_runtime.h>
#include <hip/hip_bf16.h>

typedef __attribute__((ext_vector_type(8))) short bf16x8;
typedef __attribute__((ext_vector_type(4))) float f32x4;
typedef __attribute__((ext_vector_type(2))) float f32x2;

struct Params {
  const float* x[6];
  const float* W[6];
  const float* cg;
  float* out;
  unsigned short* Wb;   // ws: W pre-swizzled to bf16 B-fragment order (4,091,904 B)
};

constexpr int NPAIRS_C[6] = {6, 15, 21, 24, 24, 21};
constexpr int POFF_C[6]   = {0, 6, 21, 42, 66, 90};
constexpr size_t WBASE_C[6] = {0, 110592, 387072, 774144, 1216512, 1658880};
constexpr int KL_C[6]   = {3456, 8640, 12096, 13824, 13824, 12096};
constexpr int LOFF_C[6] = {0, 1, 4, 9, 16, 25};   // row offset of l in xall

constexpr int TL1[111] = {
  0,1,2,3,4,5,
  0,1,1,1,2,2,2,3,3,3,4,4,4,5,5,
  0,1,1,1,2,2,2,2,2,3,3,3,3,3,4,4,4,4,5,5,5,
  0,1,1,1,2,2,2,2,2,3,3,3,3,3,3,4,4,4,4,4,5,5,5,5,
  0,1,1,1,2,2,2,2,3,3,3,3,3,4,4,4,4,4,4,5,5,5,5,5,
  0,1,1,2,2,2,3,3,3,3,4,4,4,4,4,5,5,5,5,5,5
};
constexpr int TL2R[111] = {
  0,1,2,3,4,5,
  1,0,1,2,1,2,3,2,3,4,3,4,5,4,5,
  2,1,2,3,0,1,2,3,4,1,2,3,4,5,2,3,4,5,3,4,5,
  3,2,3,4,1,2,3,4,5,0,1,2,3,4,5,1,2,3,4,5,2,3,4,5,
  4,3,4,5,2,3,4,5,1,2,3,4,5,0,1,2,3,4,5,1,2,3,4,5,
  5,4,5,3,4,5,2,3,4,5,1,2,3,4,5,0,1,2,3,4,5
};

__constant__ int c_l1[111] = {
  0,1,2,3,4,5,
  0,1,1,1,2,2,2,3,3,3,4,4,4,5,5,
  0,1,1,1,2,2,2,2,2,3,3,3,3,3,4,4,4,4,5,5,5,
  0,1,1,1,2,2,2,2,2,3,3,3,3,3,3,4,4,4,4,4,5,5,5,5,
  0,1,1,1,2,2,2,2,3,3,3,3,3,4,4,4,4,4,4,5,5,5,5,5,
  0,1,1,2,2,2,3,3,3,3,4,4,4,4,4,5,5,5,5,5,5
};
__constant__ int c_l2[111] = {
  0,1,2,3,4,5,
  1,0,1,2,1,2,3,2,3,4,3,4,5,4,5,
  2,1,2,3,0,1,2,3,4,1,2,3,4,5,2,3,4,5,3,4,5,
  3,2,3,4,1,2,3,4,5,0,1,2,3,4,5,1,2,3,4,5,2,3,4,5,
  4,3,4,5,2,3,4,5,1,2,3,4,5,0,1,2,3,4,5,1,2,3,4,5,
  5,4,5,3,4,5,2,3,4,5,1,2,3,4,5,0,1,2,3,4,5
};
// 21 (L, mp0) blocks, heavy-L first; each block covers mp0, mp0+1
__constant__ int c_mb_l[21]  = {5,5,5,5,5,5, 4,4,4,4,4, 3,3,3,3, 2,2,2, 1,1, 0};
__constant__ int c_mb_m0[21] = {0,2,4,6,8,10, 0,2,4,6,8, 0,2,4,6, 0,2,4, 0,2, 0};
// chunk-pair groups: group g = chunks (GA[g], GA[g]+3) — same d0, c differs by 4
__constant__ int c_GA[9] = {0,1,2,6,7,8,12,13,14};

// ---------- W swizzle (unchanged from R3, verified) ----------
template<int L>
__device__ __forceinline__ void swz(const Params& P, int u8) {
  constexpr int KL = KL_C[L];
  constexpr int KL8 = KL / 8;
  if (u8 >= 32 * KL8) return;
  const int h  = u8 / KL8;
  const int k  = (u8 - h * KL8) * 8;
  const int pair = k / 576;
  const int kin  = k - pair * 576;
  const int kc = kin >> 5;
  const int g  = (kin >> 3) & 3;
  const float* src = P.W[L] + (size_t)h * KL + k;
  f32x4 v0 = *(const f32x4*)src;
  f32x4 v1 = *(const f32x4*)(src + 4);
  union { __hip_bfloat162 h2; unsigned int u; } z;
  unsigned int o0, o1, o2, o3;
  z.h2 = __float22bfloat162_rn(make_float2(v0.x, v0.y)); o0 = z.u;
  z.h2 = __float22bfloat162_rn(make_float2(v0.z, v0.w)); o1 = z.u;
  z.h2 = __float22bfloat162_rn(make_float2(v1.x, v1.y)); o2 = z.u;
  z.h2 = __float22bfloat162_rn(make_float2(v1.z, v1.w)); o3 = z.u;
  const size_t dst = WBASE_C[L] + (size_t)pair * 18432 + kc * 1024 + (h >> 4) * 512
                   + ((size_t)(g * 16 + (h & 15))) * 8;
  *(uint4*)(P.Wb + dst) = make_uint4(o0, o1, o2, o3);
}

__global__ __launch_bounds__(256)
void swizzle_W(Params P) {
  const int u8 = blockIdx.x * 256 + threadIdx.x;
  switch (blockIdx.y) {
    case 0: swz<0>(P, u8); break;
    case 1: swz<1>(P, u8); break;
    case 2: swz<2>(P, u8); break;
    case 3: swz<3>(P, u8); break;
    case 4: swz<4>(P, u8); break;
    default: swz<5>(P, u8); break;
  }
}

// ---------- LDS layout (float units) ----------
// xall: [36 rows][stride 196] f32 (row = LOFF[l]+i, col = b*24+c, b<8)
//   196 % 32 == 4 -> adjacent rows shift 4 banks
#define XALL_F 0
#define CG_F   7056      // [2][NP][12] f32 <= 576
#define RED_F  7632      // [4][16][32] f32 = 2048
#define SMEM_FLOATS 9680 // 38,720 B -> 4 blocks/CU

template<int L>
__device__ __forceinline__ void body(const Params& P, const int mp0, const int btile) {
  constexpr int NP  = NPAIRS_C[L];
  constexpr int OFF = POFF_C[L];
  extern __shared__ float smem[];
  float* xall  = smem + XALL_F;
  float* cgall = smem + CG_F;
  float* red   = smem + RED_F;

  const int t    = threadIdx.x;
  const int lane = t & 63;
  const int w    = t >> 6;
  const int q8   = lane >> 4;         // A-frag k-quad
  const int rI   = lane & 15;         // A-frag row: b = rI&7, mpL = rI>>3
  const int b    = rI & 7;
  const int mpL  = rI >> 3;
  const int b0   = btile * 8;

  // ---- stage all x, transposed, fp32 ----
#pragma unroll
  for (int l = 0; l < 6; ++l) {
    const int n = 2 * l + 1;
    const float* src = P.x[l] + (size_t)b0 * 24 * n;
    const int tot = 8 * 24 * n;
    for (int e = t; e < tot; e += 256) {
      const int bc = e / n;                  // compile-time divisor
      const int i  = e - bc * n;
      xall[(LOFF_C[l] + i) * 196 + bc] = src[e];
    }
  }
  // ---- stage cg diagonals for mp0 and mp0+1 (zeros where invalid) ----
  for (int e = t; e < 2 * NP * 12; e += 256) {
    const int i  = e % 12;
    const int r  = e / 12;
    const int pi = r % NP;
    const int mL = r / NP;
    const int l1 = c_l1[OFF + pi], l2 = c_l2[OFF + pi];
    const int mp = mp0 + mL;
    const int j  = mp + l1 + l2 - L - i;
    float v = 0.f;
    if (mp <= 2 * L && i <= 2 * l1 && j >= 0 && j <= 2 * l2)
      v = P.cg[((size_t)(((l1 * 6 + l2) * 6 + L) * 11 + mp) * 11 + i) * 11 + j];
    cgall[(mL * NP + pi) * 12 + i] = v;
  }
  __syncthreads();

  f32x4 accC0 = {0.f, 0.f, 0.f, 0.f};   // h 0..15
  f32x4 accC1 = {0.f, 0.f, 0.f, 0.f};   // h 16..31
  const int colb = b * 24;

  for (int g = w; g < 9; g += 4) {          // 3/2/2/2 groups per wave
    const int kcA = c_GA[g];
    const int k0  = kcA * 32 + q8 * 8;
    const int cA  = k0 / 24;                // per-lane, once per group
    const int d0  = k0 - cA * 24;           // in {0,8,16}
    const float* x2base = xall + colb + d0;
    const float* x1base = xall + colb + cA; // x1B at +4

#pragma unroll
    for (int pi = 0; pi < NP; ++pi) {
      constexpr int dummy = 0; (void)dummy;
      const int l1 = TL1[OFF + pi], l2 = TL2R[OFF + pi];   // folded by unroll
      const int n1 = 2 * l1 + 1, n2 = 2 * l2 + 1;
      const int R1 = LOFF_C[l1], R2 = LOFF_C[l2];
      const int mK0w = mp0 + l1 + l2 - L;        // wave-uniform (mpL=0)
      const int mK0l = mK0w + mpL;               // per-lane
      const int i0 = (mK0w - (n2 - 1)) > 0 ? (mK0w - (n2 - 1)) : 0;
      const int i1 = (n1 - 1) < (mK0w + 1) ? (n1 - 1) : (mK0w + 1);

      // prefetch B-fragments (L2) — latency hides under the diag loop
      const unsigned short* wbp = P.Wb + WBASE_C[L] + (size_t)pi * 18432 + lane * 8;
      const bf16x8 wfA0 = *(const bf16x8*)(wbp + kcA * 1024);
      const bf16x8 wfA1 = *(const bf16x8*)(wbp + kcA * 1024 + 512);
      const bf16x8 wfB0 = *(const bf16x8*)(wbp + (kcA + 3) * 1024);
      const bf16x8 wfB1 = *(const bf16x8*)(wbp + (kcA + 3) * 1024 + 512);

      f32x2 pA[4], pB[4];
#pragma unroll
      for (int dd = 0; dd < 4; ++dd) { pA[dd] = (f32x2){0.f, 0.f}; pB[dd] = (f32x2){0.f, 0.f}; }

      const float* cgp = cgall + (mpL * NP + pi) * 12;
      for (int i = i0; i <= i1; ++i) {
        const float cgv = cgp[i];
        int j = mK0l - i;
        j = j < 0 ? 0 : (j > n2 - 1 ? n2 - 1 : j);   // clamped; cg==0 when out-of-diag
        const float* x2p = x2base + (R2 + j) * 196;
        f32x2 xv[4];
        *(f32x4*)&xv[0] = *(const f32x4*)x2p;
        *(f32x4*)&xv[2] = *(const f32x4*)(x2p + 4);
        const float* x1p = x1base + (R1 + i) * 196;
        const float sA = cgv * x1p[0];
        const float sB = cgv * x1p[4];
        const f32x2 svA = {sA, sA}, svB = {sB, sB};
#pragma unroll
        for (int dd = 0; dd < 4; ++dd) {
          pA[dd] += svA * xv[dd];
          pB[dd] += svB * xv[dd];
        }
      }
      // pack A-fragments and accumulate
      union { unsigned int u[4]; bf16x8 v; } zA, zB;
#pragma unroll
      for (int dd = 0; dd < 4; ++dd) {
        union { __hip_bfloat162 h2; unsigned int u; } z;
        z.h2 = __float22bfloat162_rn(make_float2(pA[dd].x, pA[dd].y)); zA.u[dd] = z.u;
        z.h2 = __float22bfloat162_rn(make_float2(pB[dd].x, pB[dd].y)); zB.u[dd] = z.u;
      }
      accC0 = __builtin_amdgcn_mfma_f32_16x16x32_bf16(zA.v, wfA0, accC0, 0, 0, 0);
      accC0 = __builtin_amdgcn_mfma_f32_16x16x32_bf16(zB.v, wfB0, accC0, 0, 0, 0);
      accC1 = __builtin_amdgcn_mfma_f32_16x16x32_bf16(zA.v, wfA1, accC1, 0, 0, 0);
      accC1 = __builtin_amdgcn_mfma_f32_16x16x32_bf16(zB.v, wfB1, accC1, 0, 0, 0);
    }
  }

  // ---- cross-wave k-reduction ----
  {
    const int col16 = lane & 15;      // D: col = h (lo half), row = (lane>>4)*4+reg
    const int rbase = (w * 16 + (lane >> 4) * 4);
#pragma unroll
    for (int r = 0; r < 4; ++r) {
      red[(rbase + r) * 32 + col16]      = accC0[r];
      red[(rbase + r) * 32 + 16 + col16] = accC1[r];
    }
  }
  __syncthreads();
#pragma unroll
  for (int it = 0; it < 2; ++it) {
    const int idx = t + 256 * it;     // 512: 16 rows x 32 h
    const int row = idx >> 5, h = idx & 31;
    const float v = red[row * 32 + h] + red[512 + row * 32 + h]
                  + red[1024 + row * 32 + h] + red[1536 + row * 32 + h];
    const int ob = row & 7, omL = row >> 3;
    const int mp = mp0 + omL;
    if (mp <= 2 * L)
      P.out[(size_t)(b0 + ob) * 1152 + h * 36 + L * L + mp] = v;
  }
}

__global__ __launch_bounds__(256, 4)
void CGLayer_main(Params P) {
  const int mb = blockIdx.x;
  const int l = c_mb_l[mb], mp0 = c_mb_m0[mb];
  const int btile = blockIdx.y;
  switch (l) {
    case 0: body<0>(P, mp0, btile); break;
    case 1: body<1>(P, mp0, btile); break;
    case 2: body<2>(P, mp0, btile); break;
    case 3: body<3>(P, mp0, btile); break;
    case 4: body<4>(P, mp0, btile); break;
    default: body<5>(P, mp0, btile); break;
  }
}

extern "C" void kernel_launch(void* const* d_in, const int* in_sizes, int n_in,
                              void* d_out, int out_size, void* d_ws, size_t ws_size,
                              hipStream_t stream) {
  Params P;
  for (int i = 0; i < 6; ++i) P.x[i] = (const float*)d_in[i];
  for (int i = 0; i < 6; ++i) P.W[i] = (const float*)d_in[6 + i];
  P.cg  = (const float*)d_in[12];
  P.out = (float*)d_out;
  P.Wb  = (unsigned short*)d_ws;   // needs 4,091,904 bytes

  dim3 sg(216, 6);
  swizzle_W<<<sg, 256, 0, stream>>>(P);
  dim3 grid(21, 32);
  CGLayer_main<<<grid, 256, SMEM_FLOATS * sizeof(float), stream>>>(P);
}